// Round 3
// 246.775 us; speedup vs baseline: 1.0209x; 1.0209x over previous
//
#include <hip/hip_runtime.h>
#include <hip/hip_bf16.h>

#define B_    4
#define N_    16384
#define K_    16
#define CIN_  64
#define CF_   67          // 3 + 64 concat channels
#define COUT_ 128
#define AGGP_ 1088        // 16*68 padded flattening (c=67 slot zero per w-row)
#define P_    16          // points per block
#define FSTR  72          // bf16 record stride in shorts (144 B)
#define ASTR  1096        // agg/FT row stride in shorts (2192 B, 16B-aligned)
#define WTS   272         // s_WT point stride in shorts: [w][k] 16x16 + 16 pad
#define NEG_  0.1f

typedef __attribute__((ext_vector_type(8))) short short8;
typedef __attribute__((ext_vector_type(4))) float f32x4;
typedef __attribute__((ext_vector_type(2))) unsigned int uint2_t;
typedef __attribute__((ext_vector_type(4))) unsigned int uint4_t;

__device__ __forceinline__ unsigned short f2b(float f) {
    __hip_bfloat16 h = __float2bfloat16(f);
    return *reinterpret_cast<unsigned short*>(&h);
}
__device__ __forceinline__ float leaky(float x) { return x >= 0.f ? x : NEG_ * x; }

// ---------------------------------------------------------------------------
// Kernel 1 (fused prep):
//  blocks [0,1024):   transpose concat(xyz,features) -> ft bf16 [B][N][FSTR]
//                     (float4 global loads, dwordx4 packed stores)
//  blocks [1024,1152): convert lin_w fp32 [128][16*67] -> lwb bf16 [128][16*68]
// ---------------------------------------------------------------------------
__global__ __launch_bounds__(256) void pc_prep(
    const float* __restrict__ xyz,
    const float* __restrict__ feats,
    const float* __restrict__ lin_w,
    unsigned short* __restrict__ ft,
    short* __restrict__ lwb)
{
    const int bid = blockIdx.x, t = threadIdx.x;
    if (bid < 1024) {
        __shared__ float st[64][69];           // [j_local][c], +1 pad
        const int b  = bid >> 8;
        const int j0 = (bid & 255) << 6;
        // load: lane = (c, jq); float4 per thread, coalesced 1 KB per wave instr
        for (int ii = t; ii < 68 * 16; ii += 256) {
            const int c = ii >> 4, jq = ii & 15;
            f32x4 v = {0.f, 0.f, 0.f, 0.f};
            if (c < 3)
                v = *(const f32x4*)(xyz   + ((size_t)b * 3    + c)       * N_ + j0 + 4 * jq);
            else if (c < CF_)
                v = *(const f32x4*)(feats + ((size_t)b * CIN_ + (c - 3)) * N_ + j0 + 4 * jq);
            st[4 * jq + 0][c] = v.x;
            st[4 * jq + 1][c] = v.y;
            st[4 * jq + 2][c] = v.z;
            st[4 * jq + 3][c] = v.w;
        }
        __syncthreads();
        // pack: 9 x uint4 per record (72 shorts), coalesced 16-B stores
        uint4_t* outp4 = (uint4_t*)(ft + (size_t)(b * N_ + j0) * FSTR);
        for (int idx = t; idx < 64 * 9; idx += 256) {
            const int j2 = idx / 9, q = idx - 9 * j2;
            const int cb = q * 8;
            unsigned u[4];
#pragma unroll
            for (int e = 0; e < 4; e++) {
                const int c0 = cb + 2 * e;
                const unsigned lo = (c0     < CF_) ? (unsigned)f2b(st[j2][c0])     : 0u;
                const unsigned hi = (c0 + 1 < CF_) ? (unsigned)f2b(st[j2][c0 + 1]) : 0u;
                u[e] = lo | (hi << 16);
            }
            uint4_t uu = { u[0], u[1], u[2], u[3] };
            outp4[idx] = uu;
        }
    } else {
        const int o = bid - 1024;              // 128 out-channel rows
        const float* src = lin_w + (size_t)o * (16 * CF_);
        short*       dst = lwb   + (size_t)o * AGGP_;
        for (int i = t; i < AGGP_; i += 256) {
            const int w = i / 68, c = i % 68;
            dst[i] = (c < CF_) ? (short)f2b(src[w * CF_ + c]) : (short)0;
        }
    }
}

// ---------------------------------------------------------------------------
// Kernel 2: fused weight-net MLP + MFMA agg einsum + MFMA final linear.
// Phases 1-2 wave-local (wave owns 4 points); single barrier before phase 3.
// FT[c][k] half-slots are parity-swizzled by s (=c>>2): for odd s the k0..7
// half lives at slot 8 and k8..15 at slot 0.  Only the store ADDRESS
// alternates (data is always q0 at slot hf, q1 at slot 8-hf) — round-1 bug
// was selecting data by parity too, which cancelled the address swap and
// left storage unswizzled while the read compensated.  Phase-2b reads undo
// via khs = kh ^ ((pr&4)<<1); rows 64..67 (s=16, even parity; active lanes
// have pr&4==0) stay unswizzled, matching the tail writes.
// Phase 3 uses a 6-deep register prefetch ring on the lwb A-panel
// (L2-resident, ~200-600cy loaded latency; old 1-deep prefetch gave ~30cy
// slack -> per-iter stall was the dominant kernel cost).
// LDS 44.8 KB -> 3 blocks/CU.  __launch_bounds__(256,2): VGPR cap 128.
// ---------------------------------------------------------------------------
__global__ __launch_bounds__(256, 2) void pc_main(
    const float*          __restrict__ xyz,
    const unsigned short* __restrict__ ft,
    const int*            __restrict__ knn,
    const float* __restrict__ w1, const float* __restrict__ b1,
    const float* __restrict__ w2, const float* __restrict__ b2,
    const short* __restrict__ lwb, const float* __restrict__ lin_b,
    float* __restrict__ out)
{
    __shared__ __align__(16) short s_agg[P_ * ASTR];   // FT[c][k] then agg[w*68+c]
    __shared__ __align__(16) short s_WT[P_ * WTS];     // [p][w*16+k] bf16
    __shared__ int s_idx[P_ * K_];

    const int t   = threadIdx.x;
    const int bid = blockIdx.x;            // 4096
    const int b   = bid >> 10;
    const int n0  = (bid & 1023) << 4;
    const unsigned short* ftb = ft + (size_t)b * N_ * FSTR;

    // ---------------- phase 1: weight-net MLP, one thread per (p,k) --------
    {
        const int p = t >> 4, k = t & 15;
        const int n = n0 + p;
        const int j = knn[((size_t)(b * N_ + n)) * K_ + k];
        s_idx[p * K_ + k] = j;
        const float* xb = xyz + (size_t)b * 3 * N_;   // fp32-exact MLP input
        const float dx0 = xb[j]          - xb[n];
        const float dx1 = xb[N_ + j]     - xb[N_ + n];
        const float dx2 = xb[2 * N_ + j] - xb[2 * N_ + n];
        float h[8];
#pragma unroll
        for (int i = 0; i < 8; i++)
            h[i] = leaky(b1[i] + w1[i*3+0]*dx0 + w1[i*3+1]*dx1 + w1[i*3+2]*dx2);
        short* wd = s_WT + p * WTS + k;               // WT[p][w][k], stride 16
#pragma unroll
        for (int w = 0; w < 16; w++) {
            float a = b2[w];
#pragma unroll
            for (int i = 0; i < 8; i++) a += w2[w*8+i] * h[i];
            wd[w * 16] = (short)f2b(leaky(a));
        }
    }
    __asm__ __volatile__("" ::: "memory");   // wave-local: DS pipe in-order

    // ---------------- phase 2a: gather + register transpose -> FT[c][k] ----
    {
        const int p = t >> 4, s = t & 15;
        const int* ip = s_idx + p * K_;
        const bool tl = (s < 3);
        uint2_t fb[K_];
        unsigned feu[8] = {0,0,0,0,0,0,0,0};
#pragma unroll
        for (int k = 0; k < K_; k++) {
            const unsigned short* rec = ftb + (size_t)ip[k] * FSTR;
            fb[k] = *(const uint2_t*)(rec + 4 * s);
            if (tl) feu[k >> 1] |= ((unsigned)rec[64 + s]) << (16 * (k & 1));
        }
        short* frow = s_agg + p * ASTR;
        const int swz = s & 1;               // parity half-swizzle (s == c>>2)
        const int hf  = swz << 3;            // first-store slot: 0 (even) / 8 (odd)
#pragma unroll
        for (int i = 0; i < 4; i++) {        // rows c = 4s+i, k-contiguous
            const unsigned sel = (i & 1) ? 0x07060302u : 0x05040100u;
            unsigned pk[8];
#pragma unroll
            for (int d = 0; d < 8; d++) {
                const unsigned lo = (i < 2) ? fb[2*d].x   : fb[2*d].y;
                const unsigned hi = (i < 2) ? fb[2*d+1].x : fb[2*d+1].y;
                pk[d] = __builtin_amdgcn_perm(hi, lo, sel);
            }
            const int c = 4 * s + i;
            uint4_t q0 = { pk[0], pk[1], pk[2], pk[3] };   // logical k = 0..7
            uint4_t q1 = { pk[4], pk[5], pk[6], pk[7] };   // logical k = 8..15
            // address alternates by parity; data does NOT (q0 always to hf).
            // odd rows: k0..7 at slot 8, k8..15 at slot 0  (swizzled layout)
            *(uint4_t*)(frow + c * 16 + hf)       = q0;
            *(uint4_t*)(frow + c * 16 + (8 - hf)) = q1;
        }
        if (tl) {                            // tail rows c = 64..66 (unswizzled)
            uint4_t q0 = { feu[0], feu[1], feu[2], feu[3] };
            uint4_t q1 = { feu[4], feu[5], feu[6], feu[7] };
            *(uint4_t*)(frow + (64 + s) * 16)     = q0;
            *(uint4_t*)(frow + (64 + s) * 16 + 8) = q1;
        }
        if (s == 3) {                        // row 67 = zero (agg[w][67]=0)
            uint4_t z = {0u, 0u, 0u, 0u};
            *(uint4_t*)(frow + 67 * 16)     = z;
            *(uint4_t*)(frow + 67 * 16 + 8) = z;
        }
    }
    __asm__ __volatile__("" ::: "memory");

    // ---------------- phase 2b: pair MFMA agg, overwrite FT with agg -------
    {
        const int lane = t & 63;
        const int wq   = lane >> 4;          // quad
        const int pr   = lane & 15;
        const int pb   = (t >> 6) * 4;       // wave's first point
        const int kh   = (wq & 1) * 8;       // k-halfword within a point
        const int khs  = kh ^ ((pr & 4) << 1);   // undo parity half-swizzle
        const int side = (wq < 2) ? 0 : 1;   // B-operand / D-row point select
        const int asid = (pr < 8) ? 0 : 1;   // A-operand point select
        const bool act = (side == asid);
        const int cq   = 4 * (wq & 1);
#pragma unroll
        for (int pair = 0; pair < 2; pair++) {
            const int pA = pb + 2 * pair;
            const short8 bfr = *(const short8*)(s_WT + (pA + side) * WTS + pr * 16 + kh);
            const short* ap  = s_agg + (size_t)(pA + asid) * ASTR + (pr & 7) * 16 + khs;
            f32x4 D[9];
#pragma unroll
            for (int cc = 0; cc < 9; cc++) {
                short8 af = {0,0,0,0,0,0,0,0};
                // cc=8 reads rows 64..67 only; active lanes there have pr&4==0
                // so khs==kh (rows 64..67 stored unswizzled).
                if (act && (cc < 8 || (pr & 7) < 4))
                    af = *(const short8*)(ap + 128 * cc);
                D[cc] = __builtin_amdgcn_mfma_f32_16x16x32_bf16(
                            af, bfr, (f32x4){0.f,0.f,0.f,0.f}, 0, 0, 0);
            }
            __asm__ __volatile__("" ::: "memory");  // all FT reads before stores
            short* arow = s_agg + (size_t)(pA + side) * ASTR + pr * 68;  // w=pr
#pragma unroll
            for (int cc = 0; cc < 9; cc++) {
                if (cc == 8 && cq != 0) continue;   // c=68..71 skipped
                const unsigned lo = (unsigned)f2b(D[cc].x) | ((unsigned)f2b(D[cc].y) << 16);
                const unsigned hi = (unsigned)f2b(D[cc].z) | ((unsigned)f2b(D[cc].w) << 16);
                uint2_t pk2 = { lo, hi };
                *(uint2_t*)(arow + 8 * cc + cq) = pk2;
            }
        }
    }
    __syncthreads();   // agg complete for all 16 points

    // ---------------- phase 3: out[128 x 16] = L[128x1088] @ aggT^T --------
    {
        const int lane = t & 63, wid = t >> 6;
        const int quad = lane >> 4, pr = lane & 15;
        const int kq = quad * 8;
        // A fragment: lane holds A[m=pr][k=quad*8+j]; A row = out channel
        const short* a0p = lwb + (size_t)(wid * 32 + pr) * AGGP_ + kq;
        const short* a1p = a0p + 16 * AGGP_;
        // B fragment: lane holds B[k=quad*8+j][n=pr]; B col = point
        const short* bp  = s_agg + pr * ASTR + kq;
        f32x4 acc0 = {0.f, 0.f, 0.f, 0.f};
        f32x4 acc1 = {0.f, 0.f, 0.f, 0.f};

        // 6-deep register prefetch ring: ~6 iters of slack (vs 1 before) so
        // the L2 hit latency of the lwb panel loads is hidden by MFMA issue
        // + 3-wave/SIMD round-robin.  12 x short8 = 48 VGPRs, cap 128 ok.
        short8 pa0[6], pa1[6];
#pragma unroll
        for (int d = 0; d < 6; d++) {
            pa0[d] = *(const short8*)(a0p + 32 * d);
            pa1[d] = *(const short8*)(a1p + 32 * d);
        }
#pragma unroll
        for (int ks = 0; ks < 34; ks++) {
            const int d = ks % 6;                      // static under full unroll
            const short8 a0c = pa0[d], a1c = pa1[d];
            if (ks + 6 < 34) {
                pa0[d] = *(const short8*)(a0p + 32 * (ks + 6));
                pa1[d] = *(const short8*)(a1p + 32 * (ks + 6));
            }
            const short8 bfr = *(const short8*)(bp + 32 * ks);
            acc0 = __builtin_amdgcn_mfma_f32_16x16x32_bf16(a0c, bfr, acc0, 0, 0, 0);
            acc1 = __builtin_amdgcn_mfma_f32_16x16x32_bf16(a1c, bfr, acc1, 0, 0, 0);
        }
        // epilogue: D row = quad*4 + r (out channel within tile), D col = pr
        const int o0 = wid * 32 + quad * 4;
#pragma unroll
        for (int r = 0; r < 4; r++) {
            const int oA = o0 + r;
            const int oB = oA + 16;
            const float vA = leaky(acc0[r] + lin_b[oA]);
            const float vB = leaky(acc1[r] + lin_b[oB]);
            out[((size_t)(b * COUT_ + oA)) * N_ + n0 + pr] = vA;
            out[((size_t)(b * COUT_ + oB)) * N_ + n0 + pr] = vB;
        }
    }
}

extern "C" void kernel_launch(void* const* d_in, const int* in_sizes, int n_in,
                              void* d_out, int out_size, void* d_ws, size_t ws_size,
                              hipStream_t stream)
{
    const float* xyz   = (const float*)d_in[0];
    const float* feats = (const float*)d_in[1];
    const int*   knn   = (const int*)d_in[2];
    const float* w1    = (const float*)d_in[3];
    const float* b1    = (const float*)d_in[4];
    const float* w2    = (const float*)d_in[5];
    const float* b2    = (const float*)d_in[6];
    const float* lin_w = (const float*)d_in[7];
    const float* lin_b = (const float*)d_in[8];
    float* out = (float*)d_out;

    unsigned short* ft = (unsigned short*)d_ws;              // 9.44 MB bf16
    short* lwb = (short*)((char*)d_ws + (size_t)B_ * N_ * FSTR * sizeof(short));
                                                             // 128*1088*2 = 278 KB

    hipLaunchKernelGGL(pc_prep, dim3(1024 + COUT_), dim3(256), 0, stream,
                       xyz, feats, lin_w, ft, lwb);
    hipLaunchKernelGGL(pc_main, dim3(B_ * (N_ / P_)), dim3(256), 0, stream,
                       xyz, ft, knn, w1, b1, w2, b2, lwb, lin_b, out);
}